// Round 3
// baseline (447.008 us; speedup 1.0000x reference)
//
#include <hip/hip_runtime.h>
#include <math.h>

#define B 16
#define C 2
#define T 2000
#define F 257
#define NC 50            // chunks per (b,f)
#define L  (T / NC)      // 40 timesteps per chunk

#define RES_SIZE   (B * C * T * F * 2)   // 32,896,000 floats
#define OFF_SFINAL (RES_SIZE)            // + B*F
#define OFF_SMOOTH (RES_SIZE + B * F)    // + B*T*F

#define NCHUNK_BLOCKS (B * NC)           // 800
#define NCH1_BLOCKS   1200
#define BLOCK_DIM     320                // 5 waves; 257 active lanes in chunk phases

// ch1 float4 geometry: each b's ch1 slab = T*F complex = 1,028,000 floats = 257,000 float4
#define CH1_F4_PER_B  257000
#define CH1_F4_TOTAL  (B * CH1_F4_PER_B) // 4,112,000

__device__ __forceinline__ float sigmoidf_(float x) {
    return 1.0f / (1.0f + expf(-x));
}

__global__ __launch_bounds__(BLOCK_DIM) void fused_kernel(
        const float* __restrict__ input,
        const float* __restrict__ s_1,
        const float* __restrict__ weights,
        const float* __restrict__ bias,
        const float* __restrict__ alpha_param,
        float* __restrict__ out,
        int* __restrict__ cnt,          // [B]
        int* __restrict__ scanflag,     // [B]
        float* __restrict__ carries,    // [B*NC*F]
        float* __restrict__ chunkstart) // [B*NC*F]  start state for chunk c
{
    const int bid = blockIdx.x;

    if (bid < NCHUNK_BLOCKS) {
        // ---- chunk block for (b, c), channel 0 ----
        const int b = bid % B;       // bids 0..15 are c=0
        const int c = bid / B;
        const int f = threadIdx.x;
        const bool active = (f < F);

        float a = 0.f, beta = 0.f;
        if (active) {
            a = sigmoidf_(alpha_param[f]);
            beta = 1.0f - a;
        }

        const float2* inp = (const float2*)input + ((size_t)(b * C + 0) * T + (size_t)c * L) * F + f;

        // Phase 1: local carry (recurrence from 0 over L steps)
        if (active) {
            float s = 0.0f;
#pragma unroll 4
            for (int t = 0; t < L; ++t) {
                float2 v = inp[(size_t)t * F];
                float x = v.x * v.x + v.y * v.y;
                s = beta * s + a * x;
            }
            __hip_atomic_store(&carries[(b * NC + c) * F + f], s,
                               __ATOMIC_RELAXED, __HIP_MEMORY_SCOPE_AGENT);
        }
        __syncthreads();
        if (threadIdx.x == 0) {
            __threadfence();
            atomicAdd(&cnt[b], 1);   // device-scope by default
        }

        if (c == 0) {
            // Phase 2: this block performs the chunk-scan for its b
            if (threadIdx.x == 0) {
                while (__hip_atomic_load(&cnt[b], __ATOMIC_RELAXED, __HIP_MEMORY_SCOPE_AGENT) < NC) {
                    __builtin_amdgcn_s_sleep(2);
                }
            }
            __syncthreads();
            __threadfence();
            if (active) {
                float bL = 1.0f;
#pragma unroll
                for (int i = 0; i < L; ++i) bL *= beta;
                float s = s_1[b * F + f];
                for (int c2 = 0; c2 < NC; ++c2) {
                    __hip_atomic_store(&chunkstart[(b * NC + c2) * F + f], s,
                                       __ATOMIC_RELAXED, __HIP_MEMORY_SCOPE_AGENT);
                    float cr = __hip_atomic_load(&carries[(b * NC + c2) * F + f],
                                                 __ATOMIC_RELAXED, __HIP_MEMORY_SCOPE_AGENT);
                    s = bL * s + cr;
                }
                out[OFF_SFINAL + b * F + f] = s;   // s_final
            }
            __syncthreads();
            if (threadIdx.x == 0) {
                __threadfence();
                __hip_atomic_store(&scanflag[b], 1, __ATOMIC_RELAXED, __HIP_MEMORY_SCOPE_AGENT);
            }
        } else {
            if (threadIdx.x == 0) {
                while (__hip_atomic_load(&scanflag[b], __ATOMIC_RELAXED, __HIP_MEMORY_SCOPE_AGENT) == 0) {
                    __builtin_amdgcn_s_sleep(2);
                }
            }
            __syncthreads();
            __threadfence();
        }

        // Phase 3: exact per-step recurrence from chunk-start; write res ch0 + smooth
        if (active) {
            const float w0 = weights[0 * F + f];
            const float b0 = bias[0 * F + f];
            float s = __hip_atomic_load(&chunkstart[(b * NC + c) * F + f],
                                        __ATOMIC_RELAXED, __HIP_MEMORY_SCOPE_AGENT);
            float2* res = (float2*)out + ((size_t)(b * C + 0) * T + (size_t)c * L) * F + f;
            float* smooth = out + OFF_SMOOTH + ((size_t)b * T + (size_t)c * L) * F + f;
#pragma unroll 4
            for (int t = 0; t < L; ++t) {
                float2 v = inp[(size_t)t * F];
                float x = v.x * v.x + v.y * v.y;
                s = beta * s + a * x;
                float sm = sqrtf(s);
                float inv = 1.0f / (sm + 1e-8f);
                float2 rr;
                rr.x = v.x * inv * w0 + b0;
                rr.y = v.y * inv * w0 + b0;
                res[(size_t)t * F] = rr;
                smooth[(size_t)t * F] = sm;
            }
        }
    } else {
        // ---- ch1 elementwise, float4 (2 complex per thread-iter), grid-stride ----
        const int bid2 = bid - NCHUNK_BLOCKS;
        const int stride = NCH1_BLOCKS * BLOCK_DIM;
        const float4* in4 = (const float4*)input;
        float4* out4 = (float4*)out;

        for (int w = bid2 * BLOCK_DIM + threadIdx.x; w < CH1_F4_TOTAL; w += stride) {
            int b = w / CH1_F4_PER_B;
            int r = w - b * CH1_F4_PER_B;
            size_t f4idx = (size_t)CH1_F4_PER_B * (b * 2 + 1) + r;

            float4 v = in4[f4idx];
            // two complex elements: slab-flat complex indices e0=2r, e1=2r+1
            int e0 = 2 * r;
            int f0 = e0 % F;
            int f1 = f0 + 1; if (f1 == F) f1 = 0;

            float w1a = weights[F + f0], b1a = bias[F + f0];
            float w1b = weights[F + f1], b1b = bias[F + f1];

            float x0 = v.x * v.x + v.y * v.y;
            float sm0 = sqrtf(x0);
            float inv0 = 1.0f / (sm0 + 1e-8f);
            float x1 = v.z * v.z + v.w * v.w;
            float sm1 = sqrtf(x1);
            float inv1 = 1.0f / (sm1 + 1e-8f);

            float4 rr;
            rr.x = v.x * inv0 * w1a + b1a;
            rr.y = v.y * inv0 * w1a + b1a;
            rr.z = v.z * inv1 * w1b + b1b;
            rr.w = v.w * inv1 * w1b + b1b;
            out4[f4idx] = rr;
        }
    }
}

extern "C" void kernel_launch(void* const* d_in, const int* in_sizes, int n_in,
                              void* d_out, int out_size, void* d_ws, size_t ws_size,
                              hipStream_t stream) {
    const float* input       = (const float*)d_in[0];
    const float* s_1         = (const float*)d_in[1];
    const float* weights     = (const float*)d_in[2];
    const float* bias        = (const float*)d_in[3];
    const float* alpha_param = (const float*)d_in[4];
    float* out = (float*)d_out;

    int*   cnt        = (int*)d_ws;                       // [B]
    int*   scanflag   = cnt + B;                          // [B]
    float* carries    = (float*)d_ws + 32;                // [B*NC*F]
    float* chunkstart = carries + B * NC * F;             // [B*NC*F]

    // zero the flags/counters (ws is poisoned to 0xAA before every launch)
    hipMemsetAsync(d_ws, 0, 32 * sizeof(int), stream);

    const int grid = NCHUNK_BLOCKS + NCH1_BLOCKS;         // 800 + 1200
    fused_kernel<<<grid, BLOCK_DIM, 0, stream>>>(
        input, s_1, weights, bias, alpha_param, out,
        cnt, scanflag, carries, chunkstart);
}